// Round 2
// baseline (357.356 us; speedup 1.0000x reference)
//
#include <hip/hip_runtime.h>
#include <hip/hip_bf16.h>

// Problem constants (match reference)
#define S_ 64
#define P_ 2048
#define C_ 32
#define A_ 2048
#define D_ 128
#define E_ 64

// ---------------------------------------------------------------------------
// K1: att1[s,p,e] = sum_c gs[s,p,c]*W_sn[c,e] + b_sn[e]
// 16 rows per 256-thread block; 16 lanes per row, each lane computes 4 e's.
// ---------------------------------------------------------------------------
__global__ __launch_bounds__(256) void att1_kernel(
    const float* __restrict__ gs, const float* __restrict__ Wsn,
    const float* __restrict__ bsn, float* __restrict__ att1) {
  __shared__ float4 Wl[32 * 16];   // W_sn as [c][e4] float4
  __shared__ float4 bl[16];
  __shared__ float  gl[16 * 32];   // 16 gs rows
  const int tid = threadIdx.x;

  const float4* W4 = (const float4*)Wsn;          // 512 float4
  Wl[tid]       = W4[tid];
  Wl[tid + 256] = W4[tid + 256];
  if (tid < 16) bl[tid] = ((const float4*)bsn)[tid];
  const long base = (long)blockIdx.x * (16 * 32);
  gl[tid]       = gs[base + tid];
  gl[tid + 256] = gs[base + tid + 256];
  __syncthreads();

  const int r = tid >> 4, e4 = tid & 15;
  float4 acc = bl[e4];
#pragma unroll
  for (int c = 0; c < 32; ++c) {
    const float  g = gl[r * 32 + c];
    const float4 w = Wl[c * 16 + e4];
    acc.x = fmaf(g, w.x, acc.x);
    acc.y = fmaf(g, w.y, acc.y);
    acc.z = fmaf(g, w.z, acc.z);
    acc.w = fmaf(g, w.w, acc.w);
  }
  ((float4*)att1)[((long)blockIdx.x * 16 + r) * 16 + e4] = acc;
}

// ---------------------------------------------------------------------------
// K2: att2[a,e] = sum_d de[a,d]*W_df[d,e] + b_df[e]
// Same layout: 16 rows/block, 16 lanes/row, 4 e's per lane.
// ---------------------------------------------------------------------------
__global__ __launch_bounds__(256) void att2_kernel(
    const float* __restrict__ de, const float* __restrict__ Wdf,
    const float* __restrict__ bdf, float* __restrict__ att2) {
  __shared__ float4 Wl[128 * 16];  // 32 KB
  __shared__ float4 bl[16];
  __shared__ float  dl[16 * 128];  // 8 KB
  const int tid = threadIdx.x;

  const float4* W4 = (const float4*)Wdf;          // 2048 float4
#pragma unroll
  for (int i = 0; i < 8; ++i) Wl[tid + i * 256] = W4[tid + i * 256];
  if (tid < 16) bl[tid] = ((const float4*)bdf)[tid];
  const long base = (long)blockIdx.x * (16 * 128);
#pragma unroll
  for (int i = 0; i < 8; ++i) dl[tid + i * 256] = de[base + tid + i * 256];
  __syncthreads();

  const int r = tid >> 4, e4 = tid & 15;
  float4 acc = bl[e4];
#pragma unroll 4
  for (int d = 0; d < 128; ++d) {
    const float  g = dl[r * 128 + d];
    const float4 w = Wl[d * 16 + e4];
    acc.x = fmaf(g, w.x, acc.x);
    acc.y = fmaf(g, w.y, acc.y);
    acc.z = fmaf(g, w.z, acc.z);
    acc.w = fmaf(g, w.w, acc.w);
  }
  ((float4*)att2)[((long)blockIdx.x * 16 + r) * 16 + e4] = acc;
}

// ---------------------------------------------------------------------------
// K3: per-agent fused logits -> softmax -> alpha-weighted pooling.
// One block (256 threads = 4 waves) per agent. Thread t owns pixels
// p = t, t+256, ..., t+1792 for the logit phase; pooling re-maps to
// (c = t&31, pixel-group = t>>5) so gs reads are 128B-coalesced.
// ---------------------------------------------------------------------------
__global__ __launch_bounds__(256) void fuse_kernel(
    const float* __restrict__ att1, const float* __restrict__ att2,
    const int* __restrict__ sidx, const float* __restrict__ gs,
    const float* __restrict__ wfc, float* __restrict__ out) {
  const int a   = blockIdx.x;
  const int tid = threadIdx.x;
  const int s   = sidx[a];

  __shared__ float4 a2[16];        // att2 row for this agent
  __shared__ float4 w4[16];        // w_fc
  __shared__ float  alpha[P_];     // 8 KB
  __shared__ float  red[16];
  __shared__ float  part[8][32];

  if (tid < 16) {
    a2[tid] = ((const float4*)att2)[a * 16 + tid];
    w4[tid] = ((const float4*)wfc)[tid];
  }
  __syncthreads();

  const float4* arow = (const float4*)(att1 + (long)s * P_ * E_);

  // ---- logits (b_fc omitted: constant shift is softmax-invariant) ----
  float lg[8];
  float lmax = -3.0e38f;
#pragma unroll
  for (int k = 0; k < 8; ++k) {
    const int p = tid + k * 256;
    const float4* row = arow + p * 16;
    float acc = 0.0f;
#pragma unroll
    for (int e4 = 0; e4 < 16; ++e4) {
      const float4 v = row[e4];
      const float4 t = a2[e4];
      const float4 w = w4[e4];
      float x;
      x = fmaxf(v.x + t.x, 0.0f); acc = fmaf(x, w.x, acc);
      x = fmaxf(v.y + t.y, 0.0f); acc = fmaf(x, w.y, acc);
      x = fmaxf(v.z + t.z, 0.0f); acc = fmaf(x, w.z, acc);
      x = fmaxf(v.w + t.w, 0.0f); acc = fmaf(x, w.w, acc);
    }
    lg[k] = acc;
    lmax  = fmaxf(lmax, acc);
  }

  // ---- block max ----
#pragma unroll
  for (int off = 1; off < 64; off <<= 1) lmax = fmaxf(lmax, __shfl_xor(lmax, off));
  const int wv = tid >> 6;
  if ((tid & 63) == 0) red[wv] = lmax;
  __syncthreads();
  const float m = fmaxf(fmaxf(red[0], red[1]), fmaxf(red[2], red[3]));

  // ---- exp + block sum ----
  float ev[8];
  float lsum = 0.0f;
#pragma unroll
  for (int k = 0; k < 8; ++k) {
    ev[k] = __expf(lg[k] - m);
    lsum += ev[k];
  }
#pragma unroll
  for (int off = 1; off < 64; off <<= 1) lsum += __shfl_xor(lsum, off);
  if ((tid & 63) == 0) red[8 + wv] = lsum;
  __syncthreads();
  const float invZ = 1.0f / (red[8] + red[9] + red[10] + red[11]);
#pragma unroll
  for (int k = 0; k < 8; ++k) alpha[tid + k * 256] = ev[k] * invZ;
  __syncthreads();

  // ---- pooling: out[a,c] = sum_p alpha[p]*gs[s,p,c] ----
  const int c  = tid & 31;
  const int pg = tid >> 5;   // 0..7
  const float* g = gs + (long)s * P_ * C_;
  float acc0 = 0.f, acc1 = 0.f, acc2 = 0.f, acc3 = 0.f;
  for (int p = pg; p < P_; p += 32) {
    acc0 = fmaf(alpha[p],      g[(p)      * C_ + c], acc0);
    acc1 = fmaf(alpha[p + 8],  g[(p + 8)  * C_ + c], acc1);
    acc2 = fmaf(alpha[p + 16], g[(p + 16) * C_ + c], acc2);
    acc3 = fmaf(alpha[p + 24], g[(p + 24) * C_ + c], acc3);
  }
  part[pg][c] = (acc0 + acc1) + (acc2 + acc3);
  __syncthreads();

  if (tid < 32) {
    float o = 0.0f;
#pragma unroll
    for (int i = 0; i < 8; ++i) o += part[i][tid];
    out[a * C_ + tid] = o;
  }
}

// ---------------------------------------------------------------------------
extern "C" void kernel_launch(void* const* d_in, const int* in_sizes, int n_in,
                              void* d_out, int out_size, void* d_ws, size_t ws_size,
                              hipStream_t stream) {
  const float* gs   = (const float*)d_in[0];  // [S,P,C]
  const int*   sidx = (const int*)  d_in[1];  // [A]
  const float* de   = (const float*)d_in[2];  // [A,D]
  const float* Wsn  = (const float*)d_in[3];  // [C,E]
  const float* bsn  = (const float*)d_in[4];  // [E]
  const float* Wdf  = (const float*)d_in[5];  // [D,E]
  const float* bdf  = (const float*)d_in[6];  // [E]
  const float* wfc  = (const float*)d_in[7];  // [E]
  // d_in[8] = b_fc: softmax-invariant, unused.
  float* out = (float*)d_out;

  float* att1 = (float*)d_ws;                     // S*P*E fp32 = 33.5 MB
  float* att2 = att1 + (long)S_ * P_ * E_;        // A*E fp32   = 0.5 MB

  att1_kernel<<<(S_ * P_) / 16, 256, 0, stream>>>(gs, Wsn, bsn, att1);
  att2_kernel<<<A_ / 16, 256, 0, stream>>>(de, Wdf, bdf, att2);
  fuse_kernel<<<A_, 256, 0, stream>>>(att1, att2, sidx, gs, wfc, out);
}

// Round 3
// 299.597 us; speedup vs baseline: 1.1928x; 1.1928x over previous
//
#include <hip/hip_runtime.h>
#include <hip/hip_bf16.h>

#define S_ 64
#define P_ 2048
#define C_ 32
#define A_ 2048
#define D_ 128
#define E_ 64
#define PCH 256          // pixels per chunk-block
#define NCH (P_ / PCH)   // 8

// ---------------------------------------------------------------------------
// att2[a,e] = de[a,:] @ W_df + b_df   (verified in R2)
// ---------------------------------------------------------------------------
__global__ __launch_bounds__(256) void att2_kernel(
    const float* __restrict__ de, const float* __restrict__ Wdf,
    const float* __restrict__ bdf, float* __restrict__ att2) {
  __shared__ float4 Wl[128 * 16];
  __shared__ float4 bl[16];
  __shared__ float  dl[16 * 128];
  const int tid = threadIdx.x;

  const float4* W4 = (const float4*)Wdf;
#pragma unroll
  for (int i = 0; i < 8; ++i) Wl[tid + i * 256] = W4[tid + i * 256];
  if (tid < 16) bl[tid] = ((const float4*)bdf)[tid];
  const long base = (long)blockIdx.x * (16 * 128);
#pragma unroll
  for (int i = 0; i < 8; ++i) dl[tid + i * 256] = de[base + tid + i * 256];
  __syncthreads();

  const int r = tid >> 4, e4 = tid & 15;
  float4 acc = bl[e4];
#pragma unroll 4
  for (int d = 0; d < 128; ++d) {
    const float  g = dl[r * 128 + d];
    const float4 w = Wl[d * 16 + e4];
    acc.x = fmaf(g, w.x, acc.x);
    acc.y = fmaf(g, w.y, acc.y);
    acc.z = fmaf(g, w.z, acc.z);
    acc.w = fmaf(g, w.w, acc.w);
  }
  ((float4*)att2)[((long)blockIdx.x * 16 + r) * 16 + e4] = acc;
}

// ---------------------------------------------------------------------------
// Bucket agents by scene: counts[s], lists[s*A + k] = agent id.
// ---------------------------------------------------------------------------
__global__ void scatter_kernel(const int* __restrict__ sidx,
                               int* __restrict__ counts, int* __restrict__ lists) {
  const int a = blockIdx.x * 256 + threadIdx.x;
  const int s = sidx[a];
  const int pos = atomicAdd(&counts[s], 1);
  lists[s * A_ + pos] = a;
}

// ---------------------------------------------------------------------------
// logits[a,p] = sum_e relu(att1[s,p,e] + att2[a,e]) * w_fc[e]
// Block = (scene, pixel-chunk). att1 row computed on the fly per thread.
// ---------------------------------------------------------------------------
__global__ __launch_bounds__(256) void logits_kernel(
    const float* __restrict__ gs, const float* __restrict__ Wsn,
    const float* __restrict__ bsn, const float* __restrict__ wfc,
    const float* __restrict__ att2, const int* __restrict__ counts,
    const int* __restrict__ lists, float* __restrict__ logits) {
  const int s   = blockIdx.x >> 3;
  const int p0  = (blockIdx.x & 7) * PCH;
  const int tid = threadIdx.x;

  __shared__ float  gsl[PCH][33];   // padded: bank = (p + c) % 32
  __shared__ float4 Wl[32 * 16];    // W_sn [c][e4]
  __shared__ float4 a2l[32][16];    // att2 rows for current agent group
  __shared__ int    aid[32];

  const float4* W4 = (const float4*)Wsn;
  Wl[tid]       = W4[tid];
  Wl[tid + 256] = W4[tid + 256];

  const float4* g4 = (const float4*)(gs + ((long)s * P_ + p0) * C_);
#pragma unroll
  for (int k = 0; k < 8; ++k) {
    const int f = tid + k * 256;           // float4 index within chunk
    const float4 v = g4[f];
    const int p = f >> 3, c0 = (f & 7) * 4;
    gsl[p][c0]     = v.x;
    gsl[p][c0 + 1] = v.y;
    gsl[p][c0 + 2] = v.z;
    gsl[p][c0 + 3] = v.w;
  }
  __syncthreads();

  // att1 row for pixel p0+tid, in registers
  const float4* b4 = (const float4*)bsn;
  float4 a1[16];
#pragma unroll
  for (int e4 = 0; e4 < 16; ++e4) a1[e4] = b4[e4];
#pragma unroll
  for (int c = 0; c < 32; ++c) {
    const float g = gsl[tid][c];
#pragma unroll
    for (int e4 = 0; e4 < 16; ++e4) {
      const float4 w = Wl[c * 16 + e4];
      a1[e4].x = fmaf(g, w.x, a1[e4].x);
      a1[e4].y = fmaf(g, w.y, a1[e4].y);
      a1[e4].z = fmaf(g, w.z, a1[e4].z);
      a1[e4].w = fmaf(g, w.w, a1[e4].w);
    }
  }

  const float4* wf4 = (const float4*)wfc;
  float4 wf[16];
#pragma unroll
  for (int e4 = 0; e4 < 16; ++e4) wf[e4] = wf4[e4];

  const int n_s = counts[s];
  for (int g0 = 0; g0 < n_s; g0 += 32) {
    const int m = min(32, n_s - g0);
    __syncthreads();                       // protect aid/a2l reuse
    if (tid < m) aid[tid] = lists[s * A_ + g0 + tid];
    __syncthreads();
#pragma unroll
    for (int k = 0; k < 2; ++k) {
      const int idx = tid + k * 256;       // 0..511
      const int j = idx >> 4, e4 = idx & 15;
      if (j < m) a2l[j][e4] = ((const float4*)att2)[aid[j] * 16 + e4];
    }
    __syncthreads();
    for (int j = 0; j < m; ++j) {
      float acc = 0.f;
#pragma unroll
      for (int e4 = 0; e4 < 16; ++e4) {
        const float4 t = a2l[j][e4];
        acc = fmaf(fmaxf(a1[e4].x + t.x, 0.f), wf[e4].x, acc);
        acc = fmaf(fmaxf(a1[e4].y + t.y, 0.f), wf[e4].y, acc);
        acc = fmaf(fmaxf(a1[e4].z + t.z, 0.f), wf[e4].z, acc);
        acc = fmaf(fmaxf(a1[e4].w + t.w, 0.f), wf[e4].w, acc);
      }
      logits[(long)aid[j] * P_ + p0 + tid] = acc;
    }
  }
}

// ---------------------------------------------------------------------------
// Per-agent softmax stats: stats[a] = (max, 1/sum(exp(l-max)))
// ---------------------------------------------------------------------------
__global__ __launch_bounds__(256) void stats_kernel(
    const float* __restrict__ logits, float2* __restrict__ stats) {
  const int a = blockIdx.x, tid = threadIdx.x;
  __shared__ float red[8];
  const float4* l4 = (const float4*)(logits + (long)a * P_);
  const float4 v0 = l4[tid], v1 = l4[tid + 256];
  float m = fmaxf(fmaxf(fmaxf(v0.x, v0.y), fmaxf(v0.z, v0.w)),
                  fmaxf(fmaxf(v1.x, v1.y), fmaxf(v1.z, v1.w)));
#pragma unroll
  for (int off = 1; off < 64; off <<= 1) m = fmaxf(m, __shfl_xor(m, off));
  if ((tid & 63) == 0) red[tid >> 6] = m;
  __syncthreads();
  m = fmaxf(fmaxf(red[0], red[1]), fmaxf(red[2], red[3]));

  float sum = __expf(v0.x - m) + __expf(v0.y - m) + __expf(v0.z - m) + __expf(v0.w - m)
            + __expf(v1.x - m) + __expf(v1.y - m) + __expf(v1.z - m) + __expf(v1.w - m);
#pragma unroll
  for (int off = 1; off < 64; off <<= 1) sum += __shfl_xor(sum, off);
  if ((tid & 63) == 0) red[4 + (tid >> 6)] = sum;
  __syncthreads();
  if (tid == 0) {
    const float Z = red[4] + red[5] + red[6] + red[7];
    stats[a] = make_float2(m, 1.0f / Z);
  }
}

// ---------------------------------------------------------------------------
// out[a,c] += sum_{p in chunk} exp(l[a,p]-m)*invZ * gs[s,p,c]
// Block = (scene, chunk). gs chunk (32 KB) stays L1-resident across agents.
// Double-buffered w staging: one barrier per agent.
// ---------------------------------------------------------------------------
__global__ __launch_bounds__(256) void pool_kernel(
    const float* __restrict__ logits, const float2* __restrict__ stats,
    const int* __restrict__ counts, const int* __restrict__ lists,
    const float* __restrict__ gs, float* __restrict__ out) {
  const int s   = blockIdx.x >> 3;
  const int p0  = (blockIdx.x & 7) * PCH;
  const int tid = threadIdx.x;
  const int c   = tid & 31;
  const int pg  = tid >> 5;              // 0..7

  __shared__ float  wbuf[2][PCH];
  __shared__ int    aid[32];
  __shared__ float2 sm[32];
  __shared__ float  red[32][8][33];      // 33.8 KB

  const float* gsp = gs + ((long)s * P_ + p0) * C_;
  const int n_s = counts[s];

  for (int g0 = 0; g0 < n_s; g0 += 32) {
    const int m = min(32, n_s - g0);
    __syncthreads();                     // protect aid/sm/wbuf/red reuse
    if (tid < m) {
      const int a = lists[s * A_ + g0 + tid];
      aid[tid] = a;
      sm[tid]  = stats[a];
    }
    __syncthreads();

    float acc[32];
#pragma unroll
    for (int j = 0; j < 32; ++j) acc[j] = 0.f;

#pragma unroll
    for (int j = 0; j <= 32; ++j) {
      if (j < m) {                       // phase A: alpha for agent j
        const int    a  = aid[j];
        const float2 ms = sm[j];
        const float  lg = logits[(long)a * P_ + p0 + tid];
        wbuf[j & 1][tid] = __expf(lg - ms.x) * ms.y;
      }
      if (j >= 1 && j - 1 < m) {         // phase B: pool agent j-1
        const float* wb = wbuf[(j - 1) & 1];
        float a2 = 0.f;
#pragma unroll
        for (int i = 0; i < 32; ++i) {
          const int p = pg + 8 * i;
          a2 = fmaf(wb[p], gsp[p * C_ + c], a2);
        }
        acc[j - 1] = a2;
      }
      __syncthreads();
    }

    // cross-pg reduction + atomic accumulate
#pragma unroll
    for (int j = 0; j < 32; ++j) red[j][pg][c] = acc[j];
    __syncthreads();
#pragma unroll
    for (int k = 0; k < 4; ++k) {
      const int idx = tid + k * 256;     // 0..1023
      const int j = idx >> 5, cc = idx & 31;
      if (j < m) {
        float sum = 0.f;
#pragma unroll
        for (int q = 0; q < 8; ++q) sum += red[j][q][cc];
        atomicAdd(out + (long)aid[j] * C_ + cc, sum);
      }
    }
  }
}

// ---------------------------------------------------------------------------
extern "C" void kernel_launch(void* const* d_in, const int* in_sizes, int n_in,
                              void* d_out, int out_size, void* d_ws, size_t ws_size,
                              hipStream_t stream) {
  const float* gs   = (const float*)d_in[0];  // [S,P,C]
  const int*   sidx = (const int*)  d_in[1];  // [A]
  const float* de   = (const float*)d_in[2];  // [A,D]
  const float* Wsn  = (const float*)d_in[3];  // [C,E]
  const float* bsn  = (const float*)d_in[4];  // [E]
  const float* Wdf  = (const float*)d_in[5];  // [D,E]
  const float* bdf  = (const float*)d_in[6];  // [E]
  const float* wfc  = (const float*)d_in[7];  // [E]
  // d_in[8] = b_fc: constant shift, softmax-invariant — unused.
  float* out = (float*)d_out;

  float*  att2   = (float*)d_ws;                       // A*E     = 0.5 MB
  float*  logits = att2 + (long)A_ * E_;               // A*P     = 16 MB
  float2* stats  = (float2*)(logits + (long)A_ * P_);  // A       = 16 KB
  int*    counts = (int*)(stats + A_);                 // 64
  int*    lists  = counts + 64;                        // S*A     = 0.5 MB

  hipMemsetAsync(counts, 0, 64 * sizeof(int), stream);
  hipMemsetAsync(out, 0, (size_t)out_size * sizeof(float), stream);

  att2_kernel  <<<A_ / 16,   256, 0, stream>>>(de, Wdf, bdf, att2);
  scatter_kernel<<<A_ / 256, 256, 0, stream>>>(sidx, counts, lists);
  logits_kernel<<<S_ * NCH,  256, 0, stream>>>(gs, Wsn, bsn, wfc, att2,
                                               counts, lists, logits);
  stats_kernel <<<A_,        256, 0, stream>>>(logits, stats);
  pool_kernel  <<<S_ * NCH,  256, 0, stream>>>(logits, stats, counts, lists,
                                               gs, out);
}